// Round 9
// baseline (143.725 us; speedup 1.0000x reference)
//
#include <hip/hip_runtime.h>

#define N 8192
#define IN_F 128
#define OUT_F 64
#define ALPHA 0.2f

#define RB 32        // rows per block (attention)
#define JT 128       // j-tile (K per LDS stage)
#define TB 512       // threads per block (attention)
#define JC 8         // j-chunks

typedef int          iv4    __attribute__((ext_vector_type(4)));
typedef unsigned int uv4    __attribute__((ext_vector_type(4)));
typedef unsigned int uv2    __attribute__((ext_vector_type(2)));
typedef __bf16       bf16x8 __attribute__((ext_vector_type(8)));
typedef float        f32x4  __attribute__((ext_vector_type(4)));

__device__ __forceinline__ unsigned short f2bf(float x) {  // RNE f32->bf16
  unsigned u = __float_as_uint(x);
  u += 0x7fffu + ((u >> 16) & 1u);
  return (unsigned short)(u >> 16);
}
__device__ __forceinline__ float bf2f(unsigned short b) {
  return __uint_as_float(((unsigned)b) << 16);
}

// Kernel P: pack adj>0 into a bitmask at fill-rate. Wave g packs chunks
// [g*128, (g+1)*128): 64 consecutive ints -> one 8-byte ballot word.
// bit (j%64) of word j/64  <=>  adj[row][j] > 0 (little-endian bytes).
__global__ __launch_bounds__(256) void gat_pack(
    const int* __restrict__ adj, unsigned long long* __restrict__ pb)
{
  size_t g = (size_t)blockIdx.x * 4 + (threadIdx.x >> 6);
  int lane = threadIdx.x & 63;
  const int* p = adj + g * 128 * 64 + lane;
  unsigned long long* q = pb + g * 128;
#pragma unroll 4
  for (int it = 0; it < 128; ++it) {
    int v = p[(size_t)it * 64];
    unsigned long long m = __ballot(v > 0);
    if (lane == 0) q[it] = m;
  }
}

// Kernel A: h = input @ W ; f1 = h@a1 ; f2 = h@a2 ; bmax[b] = block max f2.
// Writes h TRANSPOSED as bf16: ht[o][i]. 1024 blocks x 8 rows.
__global__ __launch_bounds__(256) void gat_prep(
    const float* __restrict__ input, const float* __restrict__ W,
    const float* __restrict__ a,
    unsigned short* __restrict__ ht, float* __restrict__ f1,
    float* __restrict__ f2, float* __restrict__ bmax)
{
  __shared__ float Ws[IN_F * OUT_F];                    // 32 KB
  __shared__ float ins[8][IN_F];                        // 4 KB
  __shared__ __align__(16) unsigned short Hts[OUT_F][8];
  __shared__ float bm[4];
  int t = threadIdx.x;

  const float4* W4 = (const float4*)W;
  float4* Ws4 = (float4*)Ws;
#pragma unroll
  for (int k = 0; k < 8; ++k) Ws4[t + 256 * k] = W4[t + 256 * k];

  int row0 = blockIdx.x * 8;
  const float4* in4 = (const float4*)(input + (size_t)row0 * IN_F);
  ((float4*)&ins[0][0])[t] = in4[t];
  __syncthreads();

  int w = t >> 6, o = t & 63;
  float a1v = a[o], a2v = a[OUT_F + o];
  float pmax = -3.4e38f;

#pragma unroll
  for (int p = 0; p < 2; ++p) {
    int r = p * 4 + w;
    int i = row0 + r;
    const float4* iv = (const float4*)&ins[r][0];
    float acc = 0.f;
#pragma unroll
    for (int k4 = 0; k4 < 32; ++k4) {
      float4 v = iv[k4];
      acc += v.x * Ws[(k4 * 4 + 0) * OUT_F + o];
      acc += v.y * Ws[(k4 * 4 + 1) * OUT_F + o];
      acc += v.z * Ws[(k4 * 4 + 2) * OUT_F + o];
      acc += v.w * Ws[(k4 * 4 + 3) * OUT_F + o];
    }
    Hts[o][r] = f2bf(acc);
    float p1 = acc * a1v, p2 = acc * a2v;
#pragma unroll
    for (int m = 32; m >= 1; m >>= 1) {
      p1 += __shfl_xor(p1, m, 64);
      p2 += __shfl_xor(p2, m, 64);
    }
    pmax = fmaxf(pmax, p2);      // butterfly left p2 in every lane
    if (o == 0) {
      f1[i] = p1;
      f2[i] = p2;
    }
  }
  if (o == 0) bm[w] = pmax;
  __syncthreads();
  if (t < 64) {
    uv4 v = *(const uv4*)&Hts[t][0];
    *(uv4*)&ht[(size_t)t * N + row0] = v;
  }
  if (t == 0)
    bmax[blockIdx.x] = fmaxf(fmaxf(bm[0], bm[1]), fmaxf(bm[2], bm[3]));
}

// Kernel B: per j-chunk partial masked-softmax attention with MFMA PV.
// Identical structure to the 84.8us champion (HtS+PS double-buffer, one
// barrier per tile, depth-1 prefetch) except the mask comes from the packed
// bitmask pb (2 byte-loads/thread/tile, L2-resident) instead of 32B of adj.
// Shift m_i = lrelu(f1[i]+gmax) is an exact upper bound (lrelu monotone),
// so chunk partial sums combine linearly.
__global__ __launch_bounds__(TB) void gat_part(
    const unsigned char* __restrict__ pb, const unsigned short* __restrict__ ht,
    const float* __restrict__ f1, const float* __restrict__ f2,
    const float* __restrict__ bmax,
    float* __restrict__ num, float* __restrict__ den, int jcc)
{
  __shared__ __align__(16) unsigned short HtS[2][OUT_F * JT]; // 2x16 KB
  __shared__ __align__(16) unsigned short PS[2][RB * JT];     // 2x8 KB
  __shared__ float F1s[RB];
  __shared__ float Ms[RB];
  __shared__ float gm[8];

  int t = threadIdx.x;
  int ib = blockIdx.x & 255;        // N/RB == 256
  int jc = blockIdx.x >> 8;
  int i0 = ib * RB;
  int T = (N / JT) / jcc;

  // global max of f2 from per-block maxima (1024 entries)
  {
    float v = fmaxf(bmax[t], bmax[t + 512]);
#pragma unroll
    for (int m = 32; m >= 1; m >>= 1) v = fmaxf(v, __shfl_xor(v, m, 64));
    if ((t & 63) == 0) gm[t >> 6] = v;
  }
  __syncthreads();
  if (t < RB) {
    float g = gm[0];
#pragma unroll
    for (int k = 1; k < 8; ++k) g = fmaxf(g, gm[k]);
    float f1v = f1[i0 + t];
    F1s[t] = f1v;
    float e = f1v + g;
    Ms[t] = e > 0.f ? e : ALPHA * e;
  }

  // P-compute identity: 32 lanes (jq, 4 j each) x 16 row-slots (rp), rows rp & rp+16
  int jq = t & 31, rp = t >> 5;
  // Ht staging identity: feature so, j-chunk sc
  int so = t >> 3, sc = t & 7;
  // MFMA identity: wave w -> (m0,n0) subtile
  int w = t >> 6, l = t & 63;
  int m0 = (w & 1) * 16, n0 = (w >> 1) * 16;
  int arow = m0 + (l & 15);
  int bcol = n0 + (l & 15);
  int kg = (l >> 4) * 16;
  unsigned aswz = (unsigned)((arow & 7) << 4);
  unsigned bswz = (unsigned)((bcol & 7) << 4);
  unsigned sswz = (unsigned)((so & 7) << 4);
  unsigned pswz = (unsigned)((rp & 7) << 4);   // rows rp and rp+16 share (r&7)

  float lsum0 = 0.f, lsum1 = 0.f;
  f32x4 acc = {0.f, 0.f, 0.f, 0.f};

  int jt0 = jc * T, jt1 = (jc + 1) * T;
  // bitmask rows: this thread's 4 j's are the (jq&1)-nibble of byte jq>>1
  const unsigned char* pr0 = pb + (size_t)(i0 + rp) * (N / 8) + (jq >> 1);
  const unsigned char* pr1 = pb + (size_t)(i0 + rp + 16) * (N / 8) + (jq >> 1);
  int nsh = (jq & 1) * 4;

  // prologue: prefetch first tile's mask bytes
  unsigned bm0 = pr0[jt0 * (JT / 8)];
  unsigned bm1 = pr1[jt0 * (JT / 8)];
  __syncthreads();   // F1s/Ms ready

  int buf = 0;
  for (int jt = jt0; jt < jt1; ++jt) {
    int j0 = jt * JT;
    char* HtSb = (char*)&HtS[buf][0];
    char* PSb = (char*)&PS[buf][0];

    // stage Ht tile (global, L2-hot), swizzled byte ^= (o&7)<<4
    {
      const unsigned short* src = ht + (size_t)so * N + j0 + sc * 8;
      uv4 h0 = *(const uv4*)(src);
      uv4 h1 = *(const uv4*)(src + 64);
      *(uv4*)(HtSb + (((unsigned)(so * 256 + sc * 16)) ^ sswz)) = h0;
      *(uv4*)(HtSb + (((unsigned)(so * 256 + 128 + sc * 16)) ^ sswz)) = h1;
    }

    // P tile from mask nibbles: p = bit ? exp(lrelu(f1+f2)-m) : 0 (bf16)
    {
      float4 fv = *(const float4*)(f2 + j0 + jq * 4);
      float e; float4 pv; uv2 w2;
      unsigned s0 = bm0 >> nsh, s1 = bm1 >> nsh;
      float f1v = F1s[rp], mv = Ms[rp];
      e = f1v + fv.x; e = e > 0.f ? e : ALPHA * e; pv.x = (s0 & 1u) ? __expf(e - mv) : 0.f;
      e = f1v + fv.y; e = e > 0.f ? e : ALPHA * e; pv.y = (s0 & 2u) ? __expf(e - mv) : 0.f;
      e = f1v + fv.z; e = e > 0.f ? e : ALPHA * e; pv.z = (s0 & 4u) ? __expf(e - mv) : 0.f;
      e = f1v + fv.w; e = e > 0.f ? e : ALPHA * e; pv.w = (s0 & 8u) ? __expf(e - mv) : 0.f;
      unsigned short b0 = f2bf(pv.x), b1 = f2bf(pv.y), b2 = f2bf(pv.z), b3 = f2bf(pv.w);
      lsum0 += (bf2f(b0) + bf2f(b1)) + (bf2f(b2) + bf2f(b3));
      w2.x = (unsigned)b0 | ((unsigned)b1 << 16);
      w2.y = (unsigned)b2 | ((unsigned)b3 << 16);
      *(uv2*)(PSb + (((unsigned)(rp * 256 + jq * 8)) ^ pswz)) = w2;
      f1v = F1s[rp + 16]; mv = Ms[rp + 16];
      e = f1v + fv.x; e = e > 0.f ? e : ALPHA * e; pv.x = (s1 & 1u) ? __expf(e - mv) : 0.f;
      e = f1v + fv.y; e = e > 0.f ? e : ALPHA * e; pv.y = (s1 & 2u) ? __expf(e - mv) : 0.f;
      e = f1v + fv.z; e = e > 0.f ? e : ALPHA * e; pv.z = (s1 & 4u) ? __expf(e - mv) : 0.f;
      e = f1v + fv.w; e = e > 0.f ? e : ALPHA * e; pv.w = (s1 & 8u) ? __expf(e - mv) : 0.f;
      b0 = f2bf(pv.x); b1 = f2bf(pv.y); b2 = f2bf(pv.z); b3 = f2bf(pv.w);
      lsum1 += (bf2f(b0) + bf2f(b1)) + (bf2f(b2) + bf2f(b3));
      w2.x = (unsigned)b0 | ((unsigned)b1 << 16);
      w2.y = (unsigned)b2 | ((unsigned)b3 << 16);
      *(uv2*)(PSb + (((unsigned)((rp + 16) * 256 + jq * 8)) ^ pswz)) = w2;
    }

    // refill mask bytes for next tile (L2-hot, lands during barrier+MFMA)
    if (jt + 1 < jt1) {
      bm0 = pr0[(jt + 1) * (JT / 8)];
      bm1 = pr1[(jt + 1) * (JT / 8)];
    }
    __syncthreads();   // buf tiles ready (dbuf protects prev-iter readers)

    // MFMA: acc += P[m0+..][k] * Ht[n0+..][k]^T over K=128
#pragma unroll
    for (int ks = 0; ks < 4; ++ks) {
      bf16x8 a8 = __builtin_bit_cast(bf16x8,
          *(const uv4*)(PSb + (((unsigned)(arow * 256 + ks * 64 + kg)) ^ aswz)));
      bf16x8 b8 = __builtin_bit_cast(bf16x8,
          *(const uv4*)(HtSb + (((unsigned)(bcol * 256 + ks * 64 + kg)) ^ bswz)));
      acc = __builtin_amdgcn_mfma_f32_16x16x32_bf16(a8, b8, acc, 0, 0, 0);
    }
    buf ^= 1;
  }

  // denominator: reduce over 32 jq lanes (within each half-wave)
#pragma unroll
  for (int m = 16; m >= 1; m >>= 1) {
    lsum0 += __shfl_xor(lsum0, m, 64);
    lsum1 += __shfl_xor(lsum1, m, 64);
  }
  if ((t & 31) == 0) {
    den[(size_t)jc * N + i0 + rp] = lsum0;
    den[(size_t)jc * N + i0 + rp + 16] = lsum1;
  }

  // numerator: C/D layout col=l&15, row=(l>>4)*4+reg  [m89-verified]
  int crow = i0 + m0 + ((l >> 4) << 2);
  float* np = num + ((size_t)jc * N + crow) * OUT_F + n0 + (l & 15);
  np[0 * OUT_F] = acc[0];
  np[1 * OUT_F] = acc[1];
  np[2 * OUT_F] = acc[2];
  np[3 * OUT_F] = acc[3];
}

// Kernel C: combine chunk partials, normalize, ELU. 512 blocks x 16 rows.
__global__ __launch_bounds__(256) void gat_reduce(
    const unsigned short* __restrict__ ht, const float* __restrict__ num,
    const float* __restrict__ den, float* __restrict__ out, int jcc)
{
  int t = threadIdx.x;
  int i = blockIdx.x * 16 + (t >> 4);
  int o4 = t & 15;

  float d = 0.f;
  for (int c = 0; c < jcc; ++c) d += den[(size_t)c * N + i];

  float a0 = 0.f, a1 = 0.f, a2 = 0.f, a3 = 0.f;
  for (int c = 0; c < jcc; ++c) {
    float4 v = *(const float4*)&num[(((size_t)c * N) + i) * OUT_F + o4 * 4];
    a0 += v.x; a1 += v.y; a2 += v.z; a3 += v.w;
  }

  if (d <= 0.f) {
    // row with zero neighbors: softmax degenerates to uniform 1/N
    a0 = a1 = a2 = a3 = 0.f;
    for (int j = 0; j < N; ++j) {
      a0 += bf2f(ht[(size_t)(o4 * 4 + 0) * N + j]);
      a1 += bf2f(ht[(size_t)(o4 * 4 + 1) * N + j]);
      a2 += bf2f(ht[(size_t)(o4 * 4 + 2) * N + j]);
      a3 += bf2f(ht[(size_t)(o4 * 4 + 3) * N + j]);
    }
    d = (float)N;
  }
  float inv = 1.f / d;
  a0 *= inv; a1 *= inv; a2 *= inv; a3 *= inv;
  float4 r4;
  r4.x = a0 > 0.f ? a0 : expm1f(a0);
  r4.y = a1 > 0.f ? a1 : expm1f(a1);
  r4.z = a2 > 0.f ? a2 : expm1f(a2);
  r4.w = a3 > 0.f ? a3 : expm1f(a3);
  *(float4*)&out[(size_t)i * OUT_F + o4 * 4] = r4;
}

extern "C" void kernel_launch(void* const* d_in, const int* in_sizes, int n_in,
                              void* d_out, int out_size, void* d_ws, size_t ws_size,
                              hipStream_t stream) {
  const float* input = (const float*)d_in[0];
  const int*   adj   = (const int*)d_in[1];
  const float* W     = (const float*)d_in[2];
  const float* a     = (const float*)d_in[3];
  float* out = (float*)d_out;

  unsigned short* ht = (unsigned short*)d_ws;        // N*64 bf16 = 1 MB
  float* f1 = (float*)(ht + (size_t)N * OUT_F);      // N
  float* f2 = f1 + N;                                // N
  float* bmax = f2 + N;                              // N/8 = 1024
  unsigned long long* pbw = (unsigned long long*)(bmax + N / 8); // N*N/64 u64 = 8 MB
  float* den = (float*)(pbw + (size_t)N * N / 64);   // JC*N
  float* num = den + (size_t)JC * N;                 // JC*N*64
  size_t need = (size_t)((char*)(num + (size_t)JC * N * OUT_F) - (char*)d_ws);

  int jcc = (ws_size >= need) ? JC : 1;

  gat_pack<<<2048, 256, 0, stream>>>(adj, pbw);
  gat_prep<<<N / 8, 256, 0, stream>>>(input, W, a, ht, f1, f2, bmax);
  gat_part<<<jcc * (N / RB), TB, 0, stream>>>((const unsigned char*)pbw, ht, f1, f2, bmax, num, den, jcc);
  gat_reduce<<<N / 16, 256, 0, stream>>>(ht, num, den, out, jcc);
}

// Round 10
// 114.964 us; speedup vs baseline: 1.2502x; 1.2502x over previous
//
#include <hip/hip_runtime.h>

#define N 8192
#define IN_F 128
#define OUT_F 64
#define ALPHA 0.2f

#define RBK 128      // rows per block (attention)
#define JT 128       // j-tile (K per MFMA phase)
#define TB 512       // threads per block (attention)
#define JC 8         // j-chunks

typedef int          iv4    __attribute__((ext_vector_type(4)));
typedef unsigned int uv4    __attribute__((ext_vector_type(4)));
typedef __bf16       bf16x8 __attribute__((ext_vector_type(8)));
typedef float        f32x4  __attribute__((ext_vector_type(4)));

__device__ __forceinline__ unsigned short f2bf(float x) {  // RNE f32->bf16
  unsigned u = __float_as_uint(x);
  u += 0x7fffu + ((u >> 16) & 1u);
  return (unsigned short)(u >> 16);
}
__device__ __forceinline__ float bf2f(unsigned short b) {
  return __uint_as_float(((unsigned)b) << 16);
}

// Kernel A: h = input @ W ; f1 = h@a1 ; f2 = h@a2 ; bmax[b] = block max f2.
// Writes h TRANSPOSED as bf16: ht[o][i]. 1024 blocks x 8 rows.
__global__ __launch_bounds__(256) void gat_prep(
    const float* __restrict__ input, const float* __restrict__ W,
    const float* __restrict__ a,
    unsigned short* __restrict__ ht, float* __restrict__ f1,
    float* __restrict__ f2, float* __restrict__ bmax)
{
  __shared__ float Ws[IN_F * OUT_F];                    // 32 KB
  __shared__ float ins[8][IN_F];                        // 4 KB
  __shared__ __align__(16) unsigned short Hts[OUT_F][8];
  __shared__ float bm[4];
  int t = threadIdx.x;

  const float4* W4 = (const float4*)W;
  float4* Ws4 = (float4*)Ws;
#pragma unroll
  for (int k = 0; k < 8; ++k) Ws4[t + 256 * k] = W4[t + 256 * k];

  int row0 = blockIdx.x * 8;
  const float4* in4 = (const float4*)(input + (size_t)row0 * IN_F);
  ((float4*)&ins[0][0])[t] = in4[t];
  __syncthreads();

  int w = t >> 6, o = t & 63;
  float a1v = a[o], a2v = a[OUT_F + o];
  float pmax = -3.4e38f;

#pragma unroll
  for (int p = 0; p < 2; ++p) {
    int r = p * 4 + w;
    int i = row0 + r;
    const float4* iv = (const float4*)&ins[r][0];
    float acc = 0.f;
#pragma unroll
    for (int k4 = 0; k4 < 32; ++k4) {
      float4 v = iv[k4];
      acc += v.x * Ws[(k4 * 4 + 0) * OUT_F + o];
      acc += v.y * Ws[(k4 * 4 + 1) * OUT_F + o];
      acc += v.z * Ws[(k4 * 4 + 2) * OUT_F + o];
      acc += v.w * Ws[(k4 * 4 + 3) * OUT_F + o];
    }
    Hts[o][r] = f2bf(acc);
    float p1 = acc * a1v, p2 = acc * a2v;
#pragma unroll
    for (int m = 32; m >= 1; m >>= 1) {
      p1 += __shfl_xor(p1, m, 64);
      p2 += __shfl_xor(p2, m, 64);
    }
    pmax = fmaxf(pmax, p2);      // butterfly left p2 in every lane
    if (o == 0) {
      f1[i] = p1;
      f2[i] = p2;
    }
  }
  if (o == 0) bm[w] = pmax;
  __syncthreads();
  if (t < 64) {
    uv4 v = *(const uv4*)&Hts[t][0];
    *(uv4*)&ht[(size_t)t * N + row0] = v;
  }
  if (t == 0)
    bmax[blockIdx.x] = fmaxf(fmaxf(bm[0], bm[1]), fmaxf(bm[2], bm[3]));
}

// Kernel B: per j-chunk partial masked-softmax attention with MFMA PV.
// REGISTER-P scheme: each lane computes exactly the P values its MFMA
// A-fragments need (row = l&15 of the wave's 16 rows, k = (l>>4)*8 + ks*32),
// so P never touches LDS. Wave owns a 16-row x 64-col output (4 col-tiles).
// Block = 8 waves x 16 rows = 128 rows. HtS is the only LDS tile
// (double-buffered, one barrier per tile). adj refilled per-ks into the same
// named registers (depth-1). Shift m_i = lrelu(f1[i]+gmax) is an exact upper
// bound (lrelu monotone), so chunk partial sums combine linearly.
__global__ __launch_bounds__(TB, 4) void gat_part(
    const int* __restrict__ adj, const unsigned short* __restrict__ ht,
    const float* __restrict__ f1, const float* __restrict__ f2,
    const float* __restrict__ bmax,
    float* __restrict__ num, float* __restrict__ den, int jcc)
{
  __shared__ __align__(16) unsigned short HtS[2][OUT_F * JT]; // 2x16 KB
  __shared__ float gm[8];

  int t = threadIdx.x;
  int ib = blockIdx.x & 63;         // N/RBK == 64
  int jc = blockIdx.x >> 6;
  int i0 = ib * RBK;
  int T = (N / JT) / jcc;

  // global max of f2 from per-block maxima (1024 entries)
  {
    float v = fmaxf(bmax[t], bmax[t + 512]);
#pragma unroll
    for (int m = 32; m >= 1; m >>= 1) v = fmaxf(v, __shfl_xor(v, m, 64));
    if ((t & 63) == 0) gm[t >> 6] = v;
  }
  __syncthreads();
  float g = gm[0];
#pragma unroll
  for (int k = 1; k < 8; ++k) g = fmaxf(g, gm[k]);

  int w = t >> 6, l = t & 63;
  int kq = l >> 4;                  // lane's k-quarter (0..3)
  int i = i0 + w * 16 + (l & 15);   // lane's OWN output row
  float f1v = f1[i];
  float e0 = f1v + g;
  float mv = e0 > 0.f ? e0 : ALPHA * e0;

  // Ht staging identity: feature so, j-chunk sc (covers 64x128 tile)
  int so = t >> 3, sc = t & 7;
  unsigned sswz = (unsigned)((so & 7) << 4);

  // MFMA B read: col = ct*16 + (l&15); (ct*16)&7==0 so swizzle = (l&7)<<4
  int kg = kq * 16;                 // byte offset of lane's 8-elem k-group
  unsigned bswz = (unsigned)((l & 7) << 4);

  float lsum = 0.f;
  f32x4 acc0 = {0.f,0.f,0.f,0.f}, acc1 = {0.f,0.f,0.f,0.f};
  f32x4 acc2 = {0.f,0.f,0.f,0.f}, acc3 = {0.f,0.f,0.f,0.f};

  int jt0 = jc * T, jt1 = (jc + 1) * T;
  const int* ar = adj + (size_t)i * N + kq * 8;   // lane's adj row + k-quarter

  // prologue: adj for first tile, all 4 ks (8 x iv4 = 32 VGPR)
  iv4 a0l = __builtin_nontemporal_load((const iv4*)(ar + jt0 * JT + 0));
  iv4 a0h = __builtin_nontemporal_load((const iv4*)(ar + jt0 * JT + 0) + 1);
  iv4 a1l = __builtin_nontemporal_load((const iv4*)(ar + jt0 * JT + 32));
  iv4 a1h = __builtin_nontemporal_load((const iv4*)(ar + jt0 * JT + 32) + 1);
  iv4 a2l = __builtin_nontemporal_load((const iv4*)(ar + jt0 * JT + 64));
  iv4 a2h = __builtin_nontemporal_load((const iv4*)(ar + jt0 * JT + 64) + 1);
  iv4 a3l = __builtin_nontemporal_load((const iv4*)(ar + jt0 * JT + 96));
  iv4 a3h = __builtin_nontemporal_load((const iv4*)(ar + jt0 * JT + 96) + 1);

  int buf = 0;

#define KS_BODY(KS, AVL, AVH)                                                 \
  {                                                                           \
    float4 fv0 = *(const float4*)(f2 + j0 + (KS) * 32 + kq * 8);              \
    float4 fv1 = *(const float4*)(f2 + j0 + (KS) * 32 + kq * 8 + 4);          \
    float e; unsigned short c0,c1,c2,c3,c4,c5,c6,c7;                          \
    e = f1v + fv0.x; e = e > 0.f ? e : ALPHA * e; c0 = (AVL.x > 0) ? f2bf(__expf(e - mv)) : 0; \
    e = f1v + fv0.y; e = e > 0.f ? e : ALPHA * e; c1 = (AVL.y > 0) ? f2bf(__expf(e - mv)) : 0; \
    e = f1v + fv0.z; e = e > 0.f ? e : ALPHA * e; c2 = (AVL.z > 0) ? f2bf(__expf(e - mv)) : 0; \
    e = f1v + fv0.w; e = e > 0.f ? e : ALPHA * e; c3 = (AVL.w > 0) ? f2bf(__expf(e - mv)) : 0; \
    e = f1v + fv1.x; e = e > 0.f ? e : ALPHA * e; c4 = (AVH.x > 0) ? f2bf(__expf(e - mv)) : 0; \
    e = f1v + fv1.y; e = e > 0.f ? e : ALPHA * e; c5 = (AVH.y > 0) ? f2bf(__expf(e - mv)) : 0; \
    e = f1v + fv1.z; e = e > 0.f ? e : ALPHA * e; c6 = (AVH.z > 0) ? f2bf(__expf(e - mv)) : 0; \
    e = f1v + fv1.w; e = e > 0.f ? e : ALPHA * e; c7 = (AVH.w > 0) ? f2bf(__expf(e - mv)) : 0; \
    lsum += ((bf2f(c0)+bf2f(c1)) + (bf2f(c2)+bf2f(c3)))                       \
          + ((bf2f(c4)+bf2f(c5)) + (bf2f(c6)+bf2f(c7)));                      \
    uv4 w4;                                                                   \
    w4.x = (unsigned)c0 | ((unsigned)c1 << 16);                               \
    w4.y = (unsigned)c2 | ((unsigned)c3 << 16);                               \
    w4.z = (unsigned)c4 | ((unsigned)c5 << 16);                               \
    w4.w = (unsigned)c6 | ((unsigned)c7 << 16);                               \
    /* refill this ks's adj regs with the NEXT tile (lands during rest) */    \
    if (jt + 1 < jt1) {                                                       \
      AVL = __builtin_nontemporal_load((const iv4*)(ar + (jt + 1) * JT + (KS) * 32)); \
      AVH = __builtin_nontemporal_load((const iv4*)(ar + (jt + 1) * JT + (KS) * 32) + 1); \
    }                                                                         \
    bf16x8 a8 = __builtin_bit_cast(bf16x8, w4);                               \
    bf16x8 b8;                                                                \
    b8 = __builtin_bit_cast(bf16x8, *(const uv4*)(HtSb + (((unsigned)((0 * 16 + (l & 15)) * 256 + (KS) * 64 + kg)) ^ bswz))); \
    acc0 = __builtin_amdgcn_mfma_f32_16x16x32_bf16(a8, b8, acc0, 0, 0, 0);    \
    b8 = __builtin_bit_cast(bf16x8, *(const uv4*)(HtSb + (((unsigned)((1 * 16 + (l & 15)) * 256 + (KS) * 64 + kg)) ^ bswz))); \
    acc1 = __builtin_amdgcn_mfma_f32_16x16x32_bf16(a8, b8, acc1, 0, 0, 0);    \
    b8 = __builtin_bit_cast(bf16x8, *(const uv4*)(HtSb + (((unsigned)((2 * 16 + (l & 15)) * 256 + (KS) * 64 + kg)) ^ bswz))); \
    acc2 = __builtin_amdgcn_mfma_f32_16x16x32_bf16(a8, b8, acc2, 0, 0, 0);    \
    b8 = __builtin_bit_cast(bf16x8, *(const uv4*)(HtSb + (((unsigned)((3 * 16 + (l & 15)) * 256 + (KS) * 64 + kg)) ^ bswz))); \
    acc3 = __builtin_amdgcn_mfma_f32_16x16x32_bf16(a8, b8, acc3, 0, 0, 0);    \
  }

  for (int jt = jt0; jt < jt1; ++jt) {
    int j0 = jt * JT;
    char* HtSb = (char*)&HtS[buf][0];

    // stage Ht tile (global, L2-hot), swizzled byte ^= (o&7)<<4
    {
      const unsigned short* src = ht + (size_t)so * N + j0 + sc * 8;
      uv4 h0 = *(const uv4*)(src);
      uv4 h1 = *(const uv4*)(src + 64);
      *(uv4*)(HtSb + (((unsigned)(so * 256 + sc * 16)) ^ sswz)) = h0;
      *(uv4*)(HtSb + (((unsigned)(so * 256 + 128 + sc * 16)) ^ sswz)) = h1;
    }
    __syncthreads();   // HtS[buf] ready (dbuf protects prev-iter readers)

    KS_BODY(0, a0l, a0h)
    KS_BODY(1, a1l, a1h)
    KS_BODY(2, a2l, a2h)
    KS_BODY(3, a3l, a3h)

    buf ^= 1;
  }
#undef KS_BODY

  // denominator: lanes {x, x+16, x+32, x+48} share row x; sum the quad
  lsum += __shfl_xor(lsum, 16, 64);
  lsum += __shfl_xor(lsum, 32, 64);
  if (l < 16)
    den[(size_t)jc * N + i] = lsum;   // i == i0 + w*16 + l here

  // numerator: C/D layout col=l&15, row=(l>>4)*4+reg  [m89-verified]
  {
    int crow = i0 + w * 16 + (kq << 2);
    float* np = num + ((size_t)jc * N + crow) * OUT_F + (l & 15);
#pragma unroll
    for (int rg = 0; rg < 4; ++rg) {
      np[(size_t)rg * OUT_F + 0]  = acc0[rg];
      np[(size_t)rg * OUT_F + 16] = acc1[rg];
      np[(size_t)rg * OUT_F + 32] = acc2[rg];
      np[(size_t)rg * OUT_F + 48] = acc3[rg];
    }
  }
}

// Kernel C: combine chunk partials, normalize, ELU. 512 blocks x 16 rows.
__global__ __launch_bounds__(256) void gat_reduce(
    const unsigned short* __restrict__ ht, const float* __restrict__ num,
    const float* __restrict__ den, float* __restrict__ out, int jcc)
{
  int t = threadIdx.x;
  int i = blockIdx.x * 16 + (t >> 4);
  int o4 = t & 15;

  float d = 0.f;
  for (int c = 0; c < jcc; ++c) d += den[(size_t)c * N + i];

  float a0 = 0.f, a1 = 0.f, a2 = 0.f, a3 = 0.f;
  for (int c = 0; c < jcc; ++c) {
    float4 v = *(const float4*)&num[(((size_t)c * N) + i) * OUT_F + o4 * 4];
    a0 += v.x; a1 += v.y; a2 += v.z; a3 += v.w;
  }

  if (d <= 0.f) {
    // row with zero neighbors: softmax degenerates to uniform 1/N
    a0 = a1 = a2 = a3 = 0.f;
    for (int j = 0; j < N; ++j) {
      a0 += bf2f(ht[(size_t)(o4 * 4 + 0) * N + j]);
      a1 += bf2f(ht[(size_t)(o4 * 4 + 1) * N + j]);
      a2 += bf2f(ht[(size_t)(o4 * 4 + 2) * N + j]);
      a3 += bf2f(ht[(size_t)(o4 * 4 + 3) * N + j]);
    }
    d = (float)N;
  }
  float inv = 1.f / d;
  a0 *= inv; a1 *= inv; a2 *= inv; a3 *= inv;
  float4 r4;
  r4.x = a0 > 0.f ? a0 : expm1f(a0);
  r4.y = a1 > 0.f ? a1 : expm1f(a1);
  r4.z = a2 > 0.f ? a2 : expm1f(a2);
  r4.w = a3 > 0.f ? a3 : expm1f(a3);
  *(float4*)&out[(size_t)i * OUT_F + o4 * 4] = r4;
}

extern "C" void kernel_launch(void* const* d_in, const int* in_sizes, int n_in,
                              void* d_out, int out_size, void* d_ws, size_t ws_size,
                              hipStream_t stream) {
  const float* input = (const float*)d_in[0];
  const int*   adj   = (const int*)d_in[1];
  const float* W     = (const float*)d_in[2];
  const float* a     = (const float*)d_in[3];
  float* out = (float*)d_out;

  unsigned short* ht = (unsigned short*)d_ws;        // N*64 bf16 = 1 MB
  float* f1 = (float*)(ht + (size_t)N * OUT_F);      // N
  float* f2 = f1 + N;                                // N
  float* bmax = f2 + N;                              // N/8 = 1024
  float* den = bmax + N / 8;                         // JC*N
  float* num = den + (size_t)JC * N;                 // JC*N*64
  size_t need = (size_t)((char*)(num + (size_t)JC * N * OUT_F) - (char*)d_ws);

  int jcc = (ws_size >= need) ? JC : 1;

  gat_prep<<<N / 8, 256, 0, stream>>>(input, W, a, ht, f1, f2, bmax);
  gat_part<<<jcc * (N / RBK), TB, 0, stream>>>(adj, ht, f1, f2, bmax, num, den, jcc);
  gat_reduce<<<N / 16, 256, 0, stream>>>(ht, num, den, out, jcc);
}

// Round 11
// 84.591 us; speedup vs baseline: 1.6990x; 1.3590x over previous
//
#include <hip/hip_runtime.h>

#define N 8192
#define IN_F 128
#define OUT_F 64
#define ALPHA 0.2f

#define RB 32        // rows per block (attention)
#define JT 128       // j-tile (K per LDS stage)
#define TB 512       // threads per block (attention)
#define JC 8         // j-chunks

typedef int          iv4    __attribute__((ext_vector_type(4)));
typedef unsigned int uv4    __attribute__((ext_vector_type(4)));
typedef unsigned int uv2    __attribute__((ext_vector_type(2)));
typedef __bf16       bf16x8 __attribute__((ext_vector_type(8)));
typedef float        f32x4  __attribute__((ext_vector_type(4)));

__device__ __forceinline__ unsigned short f2bf(float x) {  // RNE f32->bf16
  unsigned u = __float_as_uint(x);
  u += 0x7fffu + ((u >> 16) & 1u);
  return (unsigned short)(u >> 16);
}
__device__ __forceinline__ float bf2f(unsigned short b) {
  return __uint_as_float(((unsigned)b) << 16);
}

// Kernel A: h = input @ W ; f1 = h@a1 ; f2 = h@a2 ; bmax[b] = block max f2.
// Writes h TRANSPOSED as bf16: ht[o][i]. 1024 blocks x 8 rows.
__global__ __launch_bounds__(256) void gat_prep(
    const float* __restrict__ input, const float* __restrict__ W,
    const float* __restrict__ a,
    unsigned short* __restrict__ ht, float* __restrict__ f1,
    float* __restrict__ f2, float* __restrict__ bmax)
{
  __shared__ float Ws[IN_F * OUT_F];                    // 32 KB
  __shared__ float ins[8][IN_F];                        // 4 KB
  __shared__ __align__(16) unsigned short Hts[OUT_F][8];
  __shared__ float bm[4];
  int t = threadIdx.x;

  const float4* W4 = (const float4*)W;
  float4* Ws4 = (float4*)Ws;
#pragma unroll
  for (int k = 0; k < 8; ++k) Ws4[t + 256 * k] = W4[t + 256 * k];

  int row0 = blockIdx.x * 8;
  const float4* in4 = (const float4*)(input + (size_t)row0 * IN_F);
  ((float4*)&ins[0][0])[t] = in4[t];
  __syncthreads();

  int w = t >> 6, o = t & 63;
  float a1v = a[o], a2v = a[OUT_F + o];
  float pmax = -3.4e38f;

#pragma unroll
  for (int p = 0; p < 2; ++p) {
    int r = p * 4 + w;
    int i = row0 + r;
    const float4* iv = (const float4*)&ins[r][0];
    float acc = 0.f;
#pragma unroll
    for (int k4 = 0; k4 < 32; ++k4) {
      float4 v = iv[k4];
      acc += v.x * Ws[(k4 * 4 + 0) * OUT_F + o];
      acc += v.y * Ws[(k4 * 4 + 1) * OUT_F + o];
      acc += v.z * Ws[(k4 * 4 + 2) * OUT_F + o];
      acc += v.w * Ws[(k4 * 4 + 3) * OUT_F + o];
    }
    Hts[o][r] = f2bf(acc);
    float p1 = acc * a1v, p2 = acc * a2v;
#pragma unroll
    for (int m = 32; m >= 1; m >>= 1) {
      p1 += __shfl_xor(p1, m, 64);
      p2 += __shfl_xor(p2, m, 64);
    }
    pmax = fmaxf(pmax, p2);      // butterfly left p2 in every lane
    if (o == 0) {
      f1[i] = p1;
      f2[i] = p2;
    }
  }
  if (o == 0) bm[w] = pmax;
  __syncthreads();
  if (t < 64) {
    uv4 v = *(const uv4*)&Hts[t][0];
    *(uv4*)&ht[(size_t)t * N + row0] = v;
  }
  if (t == 0)
    bmax[blockIdx.x] = fmaxf(fmaxf(bm[0], bm[1]), fmaxf(bm[2], bm[3]));
}

// Kernel B: per j-chunk partial masked-softmax attention with MFMA PV.
// Double-buffered LDS tiles (HtS broadcast + PS), ONE barrier per tile,
// adj prefetched one tile ahead. CHAMPION STRUCTURE (84.8us, round 5) —
// five independent restructures (R6-R10) all regressed; do not touch.
// Shift m_i = lrelu(f1[i]+gmax) is an exact upper bound (lrelu monotone),
// so chunk partial sums combine linearly.
__global__ __launch_bounds__(TB) void gat_part(
    const int* __restrict__ adj, const unsigned short* __restrict__ ht,
    const float* __restrict__ f1, const float* __restrict__ f2,
    const float* __restrict__ bmax,
    float* __restrict__ num, float* __restrict__ den, int jcc)
{
  __shared__ __align__(16) unsigned short HtS[2][OUT_F * JT]; // 2x16 KB
  __shared__ __align__(16) unsigned short PS[2][RB * JT];     // 2x8 KB
  __shared__ float F1s[RB];
  __shared__ float Ms[RB];
  __shared__ float gm[8];

  int t = threadIdx.x;
  int ib = blockIdx.x & 255;        // N/RB == 256
  int jc = blockIdx.x >> 8;
  int i0 = ib * RB;
  int T = (N / JT) / jcc;

  // global max of f2 from per-block maxima (1024 entries)
  {
    float v = fmaxf(bmax[t], bmax[t + 512]);
#pragma unroll
    for (int m = 32; m >= 1; m >>= 1) v = fmaxf(v, __shfl_xor(v, m, 64));
    if ((t & 63) == 0) gm[t >> 6] = v;
  }
  __syncthreads();
  if (t < RB) {
    float g = gm[0];
#pragma unroll
    for (int k = 1; k < 8; ++k) g = fmaxf(g, gm[k]);
    float f1v = f1[i0 + t];
    F1s[t] = f1v;
    float e = f1v + g;
    Ms[t] = e > 0.f ? e : ALPHA * e;
  }

  // P-compute identity: 32 lanes (jq) x 16 row-slots (rp), rows rp & rp+16
  int jq = t & 31, rp = t >> 5;
  // Ht staging identity: feature so, j-chunk sc
  int so = t >> 3, sc = t & 7;
  // MFMA identity: wave w -> (m0,n0) subtile
  int w = t >> 6, l = t & 63;
  int m0 = (w & 1) * 16, n0 = (w >> 1) * 16;
  int arow = m0 + (l & 15);
  int bcol = n0 + (l & 15);
  int kg = (l >> 4) * 16;
  unsigned aswz = (unsigned)((arow & 7) << 4);
  unsigned bswz = (unsigned)((bcol & 7) << 4);
  unsigned sswz = (unsigned)((so & 7) << 4);
  unsigned pswz = (unsigned)((rp & 7) << 4);   // rows rp and rp+16 share (r&7)

  float lsum0 = 0.f, lsum1 = 0.f;
  f32x4 acc = {0.f, 0.f, 0.f, 0.f};

  int jt0 = jc * T, jt1 = (jc + 1) * T;
  const int* arow0 = adj + (size_t)(i0 + rp) * N;
  const int* arow1 = adj + (size_t)(i0 + rp + 16) * N;

  // prologue: prefetch first adj tile
  iv4 av0 = __builtin_nontemporal_load((const iv4*)(arow0 + jt0 * JT) + jq);
  iv4 av1 = __builtin_nontemporal_load((const iv4*)(arow1 + jt0 * JT) + jq);
  __syncthreads();   // F1s/Ms ready

  int buf = 0;
  for (int jt = jt0; jt < jt1; ++jt) {
    int j0 = jt * JT;
    char* HtSb = (char*)&HtS[buf][0];
    char* PSb = (char*)&PS[buf][0];

    // stage Ht tile (global, L2-hot), swizzled byte ^= (o&7)<<4
    {
      const unsigned short* src = ht + (size_t)so * N + j0 + sc * 8;
      uv4 h0 = *(const uv4*)(src);
      uv4 h1 = *(const uv4*)(src + 64);
      *(uv4*)(HtSb + (((unsigned)(so * 256 + sc * 16)) ^ sswz)) = h0;
      *(uv4*)(HtSb + (((unsigned)(so * 256 + 128 + sc * 16)) ^ sswz)) = h1;
    }

    // P tile from prefetched adj: p = adj ? exp(lrelu(f1+f2)-m) : 0 (bf16)
    {
      float4 fv = *(const float4*)(f2 + j0 + jq * 4);
      float e; float4 pv; uv2 w2;

      float f1v = F1s[rp], mv = Ms[rp];
      e = f1v + fv.x; e = e > 0.f ? e : ALPHA * e; pv.x = (av0.x > 0) ? __expf(e - mv) : 0.f;
      e = f1v + fv.y; e = e > 0.f ? e : ALPHA * e; pv.y = (av0.y > 0) ? __expf(e - mv) : 0.f;
      e = f1v + fv.z; e = e > 0.f ? e : ALPHA * e; pv.z = (av0.z > 0) ? __expf(e - mv) : 0.f;
      e = f1v + fv.w; e = e > 0.f ? e : ALPHA * e; pv.w = (av0.w > 0) ? __expf(e - mv) : 0.f;
      unsigned short b0 = f2bf(pv.x), b1 = f2bf(pv.y), b2 = f2bf(pv.z), b3 = f2bf(pv.w);
      lsum0 += (bf2f(b0) + bf2f(b1)) + (bf2f(b2) + bf2f(b3));
      w2.x = (unsigned)b0 | ((unsigned)b1 << 16);
      w2.y = (unsigned)b2 | ((unsigned)b3 << 16);
      *(uv2*)(PSb + (((unsigned)(rp * 256 + jq * 8)) ^ pswz)) = w2;

      f1v = F1s[rp + 16]; mv = Ms[rp + 16];
      e = f1v + fv.x; e = e > 0.f ? e : ALPHA * e; pv.x = (av1.x > 0) ? __expf(e - mv) : 0.f;
      e = f1v + fv.y; e = e > 0.f ? e : ALPHA * e; pv.y = (av1.y > 0) ? __expf(e - mv) : 0.f;
      e = f1v + fv.z; e = e > 0.f ? e : ALPHA * e; pv.z = (av1.z > 0) ? __expf(e - mv) : 0.f;
      e = f1v + fv.w; e = e > 0.f ? e : ALPHA * e; pv.w = (av1.w > 0) ? __expf(e - mv) : 0.f;
      b0 = f2bf(pv.x); b1 = f2bf(pv.y); b2 = f2bf(pv.z); b3 = f2bf(pv.w);
      lsum1 += (bf2f(b0) + bf2f(b1)) + (bf2f(b2) + bf2f(b3));
      w2.x = (unsigned)b0 | ((unsigned)b1 << 16);
      w2.y = (unsigned)b2 | ((unsigned)b3 << 16);
      *(uv2*)(PSb + (((unsigned)((rp + 16) * 256 + jq * 8)) ^ pswz)) = w2;
    }

    // prefetch next adj tile (lands during sync + MFMA)
    if (jt + 1 < jt1) {
      av0 = __builtin_nontemporal_load((const iv4*)(arow0 + (jt + 1) * JT) + jq);
      av1 = __builtin_nontemporal_load((const iv4*)(arow1 + (jt + 1) * JT) + jq);
    }
    __syncthreads();   // buf tiles ready (dbuf protects prev-iter readers)

    // MFMA: acc += P[m0+..][k] * Ht[n0+..][k]^T over K=128
#pragma unroll
    for (int ks = 0; ks < 4; ++ks) {
      bf16x8 a8 = __builtin_bit_cast(bf16x8,
          *(const uv4*)(PSb + (((unsigned)(arow * 256 + ks * 64 + kg)) ^ aswz)));
      bf16x8 b8 = __builtin_bit_cast(bf16x8,
          *(const uv4*)(HtSb + (((unsigned)(bcol * 256 + ks * 64 + kg)) ^ bswz)));
      acc = __builtin_amdgcn_mfma_f32_16x16x32_bf16(a8, b8, acc, 0, 0, 0);
    }
    buf ^= 1;
  }

  // denominator: reduce over 32 jq lanes (within each half-wave)
#pragma unroll
  for (int m = 16; m >= 1; m >>= 1) {
    lsum0 += __shfl_xor(lsum0, m, 64);
    lsum1 += __shfl_xor(lsum1, m, 64);
  }
  if ((t & 31) == 0) {
    den[(size_t)jc * N + i0 + rp] = lsum0;
    den[(size_t)jc * N + i0 + rp + 16] = lsum1;
  }

  // numerator: C/D layout col=l&15, row=(l>>4)*4+reg  [m89-verified]
  int crow = i0 + m0 + ((l >> 4) << 2);
  float* np = num + ((size_t)jc * N + crow) * OUT_F + n0 + (l & 15);
  np[0 * OUT_F] = acc[0];
  np[1 * OUT_F] = acc[1];
  np[2 * OUT_F] = acc[2];
  np[3 * OUT_F] = acc[3];
}

// Kernel C: combine chunk partials, normalize, ELU. 512 blocks x 16 rows.
__global__ __launch_bounds__(256) void gat_reduce(
    const unsigned short* __restrict__ ht, const float* __restrict__ num,
    const float* __restrict__ den, float* __restrict__ out, int jcc)
{
  int t = threadIdx.x;
  int i = blockIdx.x * 16 + (t >> 4);
  int o4 = t & 15;

  float d = 0.f;
  for (int c = 0; c < jcc; ++c) d += den[(size_t)c * N + i];

  float a0 = 0.f, a1 = 0.f, a2 = 0.f, a3 = 0.f;
  for (int c = 0; c < jcc; ++c) {
    float4 v = *(const float4*)&num[(((size_t)c * N) + i) * OUT_F + o4 * 4];
    a0 += v.x; a1 += v.y; a2 += v.z; a3 += v.w;
  }

  if (d <= 0.f) {
    // row with zero neighbors: softmax degenerates to uniform 1/N
    a0 = a1 = a2 = a3 = 0.f;
    for (int j = 0; j < N; ++j) {
      a0 += bf2f(ht[(size_t)(o4 * 4 + 0) * N + j]);
      a1 += bf2f(ht[(size_t)(o4 * 4 + 1) * N + j]);
      a2 += bf2f(ht[(size_t)(o4 * 4 + 2) * N + j]);
      a3 += bf2f(ht[(size_t)(o4 * 4 + 3) * N + j]);
    }
    d = (float)N;
  }
  float inv = 1.f / d;
  a0 *= inv; a1 *= inv; a2 *= inv; a3 *= inv;
  float4 r4;
  r4.x = a0 > 0.f ? a0 : expm1f(a0);
  r4.y = a1 > 0.f ? a1 : expm1f(a1);
  r4.z = a2 > 0.f ? a2 : expm1f(a2);
  r4.w = a3 > 0.f ? a3 : expm1f(a3);
  *(float4*)&out[(size_t)i * OUT_F + o4 * 4] = r4;
}

extern "C" void kernel_launch(void* const* d_in, const int* in_sizes, int n_in,
                              void* d_out, int out_size, void* d_ws, size_t ws_size,
                              hipStream_t stream) {
  const float* input = (const float*)d_in[0];
  const int*   adj   = (const int*)d_in[1];
  const float* W     = (const float*)d_in[2];
  const float* a     = (const float*)d_in[3];
  float* out = (float*)d_out;

  unsigned short* ht = (unsigned short*)d_ws;        // N*64 bf16 = 1 MB
  float* f1 = (float*)(ht + (size_t)N * OUT_F);      // N
  float* f2 = f1 + N;                                // N
  float* bmax = f2 + N;                              // N/8 = 1024
  float* den = bmax + N / 8;                         // JC*N
  float* num = den + (size_t)JC * N;                 // JC*N*64
  size_t need = (size_t)((char*)(num + (size_t)JC * N * OUT_F) - (char*)d_ws);

  int jcc = (ws_size >= need) ? JC : 1;

  gat_prep<<<N / 8, 256, 0, stream>>>(input, W, a, ht, f1, f2, bmax);
  gat_part<<<jcc * (N / RB), TB, 0, stream>>>(adj, ht, f1, f2, bmax, num, den, jcc);
  gat_reduce<<<N / 16, 256, 0, stream>>>(ht, num, den, out, jcc);
}